// Round 9
// baseline (736.422 us; speedup 1.0000x reference)
//
#include <hip/hip_runtime.h>
#include <hip/hip_bf16.h>

#define N_NODES 50000
#define N_EDGES 300000
#define DIM 256
#define MPAD 50048   // 391 * 128

typedef __attribute__((ext_vector_type(8))) _Float16 half8;
typedef __attribute__((ext_vector_type(4))) _Float16 half4;
typedef __attribute__((ext_vector_type(4))) float f32x4;

__device__ __forceinline__ void async16(const void* g, void* l) {
    __builtin_amdgcn_global_load_lds(
        (const __attribute__((address_space(1))) unsigned int*)g,
        (__attribute__((address_space(3))) unsigned int*)l, 16, 0, 0);
}

// ---------------------------------------------------------------------------
// CSR build: histogram
// ---------------------------------------------------------------------------
__global__ __launch_bounds__(256) void hist_dst(const int* __restrict__ dst,
                                                int* __restrict__ deg, int E) {
    int e = blockIdx.x * blockDim.x + threadIdx.x;
    if (e < E) atomicAdd(&deg[dst[e]], 1);
}

// ---------------------------------------------------------------------------
// Hierarchical scan, step 1: per-block (1024) exclusive scan via wave shuffles.
// ---------------------------------------------------------------------------
__global__ __launch_bounds__(1024) void scan_blk(const int* __restrict__ deg,
                                                 int* __restrict__ ptr,
                                                 int* __restrict__ bsum, int n) {
    __shared__ int wsum[16];
    __shared__ int wpre[16];
    int tid = threadIdx.x;
    int i = blockIdx.x * 1024 + tid;
    int v = (i < n) ? deg[i] : 0;
    int lane = tid & 63, w = tid >> 6;
    int s = v;
#pragma unroll
    for (int off = 1; off < 64; off <<= 1) {
        int t = __shfl_up(s, off, 64);
        if (lane >= off) s += t;
    }
    if (lane == 63) wsum[w] = s;
    __syncthreads();
    if (tid < 16) {
        int acc = 0;
        for (int j = 0; j < tid; j++) acc += wsum[j];
        wpre[tid] = acc;
    }
    __syncthreads();
    int incl = s + wpre[w];
    if (i < n) ptr[i] = incl - v;
    if (tid == 1023) bsum[blockIdx.x] = incl;
}

// ---------------------------------------------------------------------------
// Scan step 2: single wave scans block totals (nb <= 64).
// ---------------------------------------------------------------------------
__global__ __launch_bounds__(64) void scan_top(int* __restrict__ bsum,
                                               int* __restrict__ ptr,
                                               int nb, int n, int E) {
    int lane = threadIdx.x;
    int v = (lane < nb) ? bsum[lane] : 0;
    int s = v;
#pragma unroll
    for (int off = 1; off < 64; off <<= 1) {
        int t = __shfl_up(s, off, 64);
        if (lane >= off) s += t;
    }
    if (lane < nb) bsum[lane] = s - v;
    if (lane == 0) ptr[n] = E;
}

// ---------------------------------------------------------------------------
// Scan step 3: add block offset; duplicate into cursor.
// ---------------------------------------------------------------------------
__global__ __launch_bounds__(1024) void scan_add(int* __restrict__ ptr,
                                                 const int* __restrict__ bsum,
                                                 int* __restrict__ cursor, int n) {
    int i = blockIdx.x * 1024 + threadIdx.x;
    if (i < n) {
        int val = ptr[i] + bsum[blockIdx.x];
        ptr[i] = val;
        cursor[i] = val;
    }
}

// ---------------------------------------------------------------------------
// CSR build: counting-sort scatter
// ---------------------------------------------------------------------------
__global__ __launch_bounds__(256) void scatter_src(const int* __restrict__ src,
                                                   const int* __restrict__ dst,
                                                   int* __restrict__ cursor,
                                                   int* __restrict__ srcbuf, int E) {
    int e = blockIdx.x * blockDim.x + threadIdx.x;
    if (e < E) {
        int pos = atomicAdd(&cursor[dst[e]], 1);
        srcbuf[pos] = src[e];
    }
}

// ---------------------------------------------------------------------------
// x (fp32) -> fp16
// ---------------------------------------------------------------------------
__global__ __launch_bounds__(256) void x2h(const float* __restrict__ x,
                                           _Float16* __restrict__ hb) {
    size_t i = (size_t)blockIdx.x * 256 + threadIdx.x;  // float4 index
    float4 v = ((const float4*)x)[i];
    half4 o;
    o.x = (_Float16)v.x; o.y = (_Float16)v.y;
    o.z = (_Float16)v.z; o.w = (_Float16)v.w;
    ((half4*)hb)[i] = o;
}

// ---------------------------------------------------------------------------
// W (fp32, [K][N] row-major) -> Wt (fp16, [N][K]) for 10 matrices
// ---------------------------------------------------------------------------
__global__ __launch_bounds__(256) void wconv(const float* __restrict__ W1,
                                             const float* __restrict__ W2,
                                             _Float16* __restrict__ Wt) {
    int mat = blockIdx.x >> 4;
    int t = blockIdx.x & 15;
    int tr = t >> 2, tc = t & 3;
    const float* W = (mat < 5) ? (W1 + (size_t)mat * 65536)
                               : (W2 + (size_t)(mat - 5) * 65536);
    __shared__ float tile[64][65];
    int tid = threadIdx.x;
    int c = tid & 63, r0 = tid >> 6;
#pragma unroll 4
    for (int i = 0; i < 16; i++) {
        int r = r0 + i * 4;
        tile[r][c] = W[(size_t)(tr * 64 + r) * 256 + tc * 64 + c];
    }
    __syncthreads();
    _Float16* o = Wt + (size_t)mat * 65536;
#pragma unroll 4
    for (int i = 0; i < 16; i++) {
        int r = r0 + i * 4;
        o[(size_t)(tc * 64 + r) * 256 + tr * 64 + c] = (_Float16)tile[c][r];
    }
}

// ---------------------------------------------------------------------------
// Layer-0 gather (fp16 x): z[n] = (1+eps)*xh[n] + sum relu(xh[src]).
// ---------------------------------------------------------------------------
__global__ __launch_bounds__(256) void gather_h(const _Float16* __restrict__ h,
                                                const int* __restrict__ ptr,
                                                const int* __restrict__ srcbuf,
                                                _Float16* __restrict__ z,
                                                const float* __restrict__ eps) {
    int node = blockIdx.x * 4 + (threadIdx.x >> 6);
    if (node >= N_NODES) return;
    int lane = threadIdx.x & 63;
    int beg = ptr[node], end = ptr[node + 1];
    float s = 1.0f + eps[0];
    half4 hv = ((const half4*)(h + (size_t)node * DIM))[lane];
    float a0 = (float)hv.x * s, a1 = (float)hv.y * s;
    float a2 = (float)hv.z * s, a3 = (float)hv.w * s;
    int e = beg;
    for (; e + 4 <= end; e += 4) {
        int s0 = srcbuf[e], s1 = srcbuf[e + 1], s2 = srcbuf[e + 2], s3 = srcbuf[e + 3];
        half4 v0 = ((const half4*)(h + (size_t)s0 * DIM))[lane];
        half4 v1 = ((const half4*)(h + (size_t)s1 * DIM))[lane];
        half4 v2 = ((const half4*)(h + (size_t)s2 * DIM))[lane];
        half4 v3 = ((const half4*)(h + (size_t)s3 * DIM))[lane];
        a0 += fmaxf((float)v0.x, 0.f) + fmaxf((float)v1.x, 0.f)
            + fmaxf((float)v2.x, 0.f) + fmaxf((float)v3.x, 0.f);
        a1 += fmaxf((float)v0.y, 0.f) + fmaxf((float)v1.y, 0.f)
            + fmaxf((float)v2.y, 0.f) + fmaxf((float)v3.y, 0.f);
        a2 += fmaxf((float)v0.z, 0.f) + fmaxf((float)v1.z, 0.f)
            + fmaxf((float)v2.z, 0.f) + fmaxf((float)v3.z, 0.f);
        a3 += fmaxf((float)v0.w, 0.f) + fmaxf((float)v1.w, 0.f)
            + fmaxf((float)v2.w, 0.f) + fmaxf((float)v3.w, 0.f);
    }
    for (; e < end; e++) {
        half4 v = ((const half4*)(h + (size_t)srcbuf[e] * DIM))[lane];
        a0 += fmaxf((float)v.x, 0.f); a1 += fmaxf((float)v.y, 0.f);
        a2 += fmaxf((float)v.z, 0.f); a3 += fmaxf((float)v.w, 0.f);
    }
    half4 o;
    o.x = (_Float16)a0; o.y = (_Float16)a1;
    o.z = (_Float16)a2; o.w = (_Float16)a3;
    ((half4*)(z + (size_t)node * DIM))[lane] = o;
}

// ---------------------------------------------------------------------------
// Layers 1..4 gather with fused BN2: h = relu(scale*C + shift) on the fly.
// ---------------------------------------------------------------------------
__global__ __launch_bounds__(256) void gather_bn(const _Float16* __restrict__ C,
                                                 const int* __restrict__ ptr,
                                                 const int* __restrict__ srcbuf,
                                                 _Float16* __restrict__ z,
                                                 const float* __restrict__ scsh,
                                                 const float* __restrict__ eps,
                                                 int l) {
    int node = blockIdx.x * 4 + (threadIdx.x >> 6);
    if (node >= N_NODES) return;
    int lane = threadIdx.x & 63;
    float4 sc = ((const float4*)scsh)[lane];
    float4 sh = ((const float4*)(scsh + DIM))[lane];
    int beg = ptr[node], end = ptr[node + 1];
    float s = 1.0f + eps[l];
    half4 hv = ((const half4*)(C + (size_t)node * DIM))[lane];
    float a0 = s * fmaxf((float)hv.x * sc.x + sh.x, 0.f);
    float a1 = s * fmaxf((float)hv.y * sc.y + sh.y, 0.f);
    float a2 = s * fmaxf((float)hv.z * sc.z + sh.z, 0.f);
    float a3 = s * fmaxf((float)hv.w * sc.w + sh.w, 0.f);
    int e = beg;
    for (; e + 4 <= end; e += 4) {
        int s0 = srcbuf[e], s1 = srcbuf[e + 1], s2 = srcbuf[e + 2], s3 = srcbuf[e + 3];
        half4 v0 = ((const half4*)(C + (size_t)s0 * DIM))[lane];
        half4 v1 = ((const half4*)(C + (size_t)s1 * DIM))[lane];
        half4 v2 = ((const half4*)(C + (size_t)s2 * DIM))[lane];
        half4 v3 = ((const half4*)(C + (size_t)s3 * DIM))[lane];
        a0 += fmaxf((float)v0.x * sc.x + sh.x, 0.f) + fmaxf((float)v1.x * sc.x + sh.x, 0.f)
            + fmaxf((float)v2.x * sc.x + sh.x, 0.f) + fmaxf((float)v3.x * sc.x + sh.x, 0.f);
        a1 += fmaxf((float)v0.y * sc.y + sh.y, 0.f) + fmaxf((float)v1.y * sc.y + sh.y, 0.f)
            + fmaxf((float)v2.y * sc.y + sh.y, 0.f) + fmaxf((float)v3.y * sc.y + sh.y, 0.f);
        a2 += fmaxf((float)v0.z * sc.z + sh.z, 0.f) + fmaxf((float)v1.z * sc.z + sh.z, 0.f)
            + fmaxf((float)v2.z * sc.z + sh.z, 0.f) + fmaxf((float)v3.z * sc.z + sh.z, 0.f);
        a3 += fmaxf((float)v0.w * sc.w + sh.w, 0.f) + fmaxf((float)v1.w * sc.w + sh.w, 0.f)
            + fmaxf((float)v2.w * sc.w + sh.w, 0.f) + fmaxf((float)v3.w * sc.w + sh.w, 0.f);
    }
    for (; e < end; e++) {
        half4 v = ((const half4*)(C + (size_t)srcbuf[e] * DIM))[lane];
        a0 += fmaxf((float)v.x * sc.x + sh.x, 0.f);
        a1 += fmaxf((float)v.y * sc.y + sh.y, 0.f);
        a2 += fmaxf((float)v.z * sc.z + sh.z, 0.f);
        a3 += fmaxf((float)v.w * sc.w + sh.w, 0.f);
    }
    half4 o;
    o.x = (_Float16)a0; o.y = (_Float16)a1;
    o.z = (_Float16)a2; o.w = (_Float16)a3;
    ((half4*)(z + (size_t)node * DIM))[lane] = o;
}

// ===========================================================================
// GEMM v3: 128x128 tile. A-tile (128x256, 64 KB) staged via async16 with XOR
// chunk swizzle in ONE shot (single vmcnt(0) drain + barrier). B read DIRECTLY
// from global in the unrolled K-loop (W is 128 KB, L2-hot across all blocks)
// -> compiler emits fine-grained vmcnt(N) interleaved with MFMA (AITER-style),
// no second barrier until the epilogue. Stats: 32-way replicated atomics into
// a per-GEMM dedicated buffer (no re-zeroing).
// ===========================================================================
#define GEMM_EPILOGUE                                                        \
    __syncthreads();                                                         \
    float* colsum = (float*)((char*)smem + 49152);                           \
    float* colsq = colsum + 128;                                             \
    if (tid < 128) { colsum[tid] = 0.0f; colsq[tid] = 0.0f; }                \
    _Float16* Cs = (_Float16*)smem;                                          \
    float bcol[4];                                                           \
    _Pragma("unroll")                                                        \
    for (int j = 0; j < 4; j++) bcol[j] = bias[col0 + wn + j * 16 + lrow];   \
    float csum[4] = {0.f, 0.f, 0.f, 0.f};                                    \
    float csq[4] = {0.f, 0.f, 0.f, 0.f};                                     \
    _Pragma("unroll")                                                        \
    for (int i = 0; i < 4; i++) {                                            \
        int rl = wm + i * 16 + quad * 4;                                     \
        _Pragma("unroll")                                                    \
        for (int j = 0; j < 4; j++) {                                        \
            int cl = wn + j * 16 + lrow;                                     \
            _Pragma("unroll")                                                \
            for (int r = 0; r < 4; r++) {                                    \
                float v = acc[i][j][r] + bcol[j];                            \
                Cs[(rl + r) * 136 + cl] = (_Float16)v;                       \
                if (row0 + rl + r < M) { csum[j] += v; csq[j] += v * v; }    \
            }                                                                \
        }                                                                    \
    }                                                                        \
    __syncthreads();                                                         \
    {                                                                        \
        int rgrp = lane >> 4, ch = lane & 15;                                \
        _Pragma("unroll")                                                    \
        for (int it = 0; it < 8; it++) {                                     \
            int row = wid * 32 + it * 4 + rgrp;                              \
            uint4 vv = *(const uint4*)(Cs + row * 136 + ch * 8);             \
            *(uint4*)(C + (size_t)(row0 + row) * DIM + col0 + ch * 8) = vv;  \
        }                                                                    \
    }                                                                        \
    _Pragma("unroll")                                                        \
    for (int j = 0; j < 4; j++) {                                            \
        atomicAdd(&colsum[wn + j * 16 + lrow], csum[j]);                     \
        atomicAdd(&colsq[wn + j * 16 + lrow], csq[j]);                       \
    }                                                                        \
    __syncthreads();                                                         \
    if (tid < 128) {                                                         \
        float* st = stats + (blockIdx.y & 31) * 512;                         \
        atomicAdd(&st[col0 + tid], colsum[tid]);                             \
        atomicAdd(&st[DIM + col0 + tid], colsq[tid]);                        \
    }

__global__ __launch_bounds__(256, 2) void gemm_f16(const _Float16* __restrict__ A,
                                                   const _Float16* __restrict__ Wt,
                                                   const float* __restrict__ bias,
                                                   _Float16* __restrict__ C,
                                                   float* __restrict__ stats,
                                                   int M) {
    __shared__ uint4 smem[4096];  // 64 KB: full 128x256 A-tile (swizzled)

    int tid = threadIdx.x;
    int wid = tid >> 6, lane = tid & 63;
    int quad = lane >> 4, lrow = lane & 15;
    int row0 = blockIdx.y * 128, col0 = blockIdx.x * 128;
    int wm = (wid & 1) * 64, wn = (wid >> 1) * 64;

    const char* Ab = (const char*)A;
    // Stage full A-tile: 16 async16 per thread, ONE drain.
#pragma unroll
    for (int j = 0; j < 16; j++) {
        int sbase = wid * 1024 + j * 64;   // 16B-slot base (wave-uniform)
        int s = sbase + lane;
        int m = s >> 5;                    // row (32 chunks = 512B per row)
        int cg = (s & 31) ^ (m & 7);       // swizzled source chunk
        async16(Ab + (size_t)(row0 + m) * 512 + cg * 16,
                (char*)smem + sbase * 16);
    }

    f32x4 acc[4][4] = {};
    __syncthreads();

    // K-loop: A from LDS, B direct from global (L2-hot) — no barriers inside.
#pragma unroll
    for (int kc = 0; kc < 8; kc++) {
        half8 af[4], bf[4];
#pragma unroll
        for (int t = 0; t < 4; t++) {
            int ma = wm + t * 16 + lrow;
            int ca = kc * 4 + quad;
            af[t] = *(const half8*)((const char*)smem +
                                    (ma * 32 + (ca ^ (ma & 7))) * 16);
            bf[t] = *(const half8*)(Wt + (size_t)(col0 + wn + t * 16 + lrow) * 256 +
                                    kc * 32 + quad * 8);
        }
#pragma unroll
        for (int i = 0; i < 4; i++)
#pragma unroll
            for (int j2 = 0; j2 < 4; j2++)
                acc[i][j2] = __builtin_amdgcn_mfma_f32_16x16x32_f16(
                    af[i], bf[j2], acc[i][j2], 0, 0, 0);
    }

    GEMM_EPILOGUE
}

// Same GEMM with fused input BN1+ReLU (scale/shift held in registers).
__global__ __launch_bounds__(256, 2) void gemm_bn(const _Float16* __restrict__ A,
                                                  const _Float16* __restrict__ Wt,
                                                  const float* __restrict__ bias,
                                                  const float* __restrict__ scsh,
                                                  _Float16* __restrict__ C,
                                                  float* __restrict__ stats,
                                                  int M) {
    __shared__ uint4 smem[4096];  // 64 KB

    int tid = threadIdx.x;
    int wid = tid >> 6, lane = tid & 63;
    int quad = lane >> 4, lrow = lane & 15;
    int row0 = blockIdx.y * 128, col0 = blockIdx.x * 128;
    int wm = (wid & 1) * 64, wn = (wid >> 1) * 64;

    const char* Ab = (const char*)A;
#pragma unroll
    for (int j = 0; j < 16; j++) {
        int sbase = wid * 1024 + j * 64;
        int s = sbase + lane;
        int m = s >> 5;
        int cg = (s & 31) ^ (m & 7);
        async16(Ab + (size_t)(row0 + m) * 512 + cg * 16,
                (char*)smem + sbase * 16);
    }

    // Per-lane BN1 scale/shift fragments for all 8 k-chunks (fp16, regs)
    half8 scv[8], shv[8];
#pragma unroll
    for (int cc = 0; cc < 8; cc++) {
        int kk = cc * 32 + quad * 8;
        float4 s0 = *(const float4*)(scsh + kk);
        float4 s1 = *(const float4*)(scsh + kk + 4);
        float4 h0 = *(const float4*)(scsh + DIM + kk);
        float4 h1 = *(const float4*)(scsh + DIM + kk + 4);
        half8 sv = {(_Float16)s0.x, (_Float16)s0.y, (_Float16)s0.z, (_Float16)s0.w,
                    (_Float16)s1.x, (_Float16)s1.y, (_Float16)s1.z, (_Float16)s1.w};
        half8 hv = {(_Float16)h0.x, (_Float16)h0.y, (_Float16)h0.z, (_Float16)h0.w,
                    (_Float16)h1.x, (_Float16)h1.y, (_Float16)h1.z, (_Float16)h1.w};
        scv[cc] = sv;
        shv[cc] = hv;
    }

    f32x4 acc[4][4] = {};
    const half8 zerov = {0, 0, 0, 0, 0, 0, 0, 0};
    __syncthreads();

#pragma unroll
    for (int kc = 0; kc < 8; kc++) {
        half8 af[4], bf[4];
        half8 sv = scv[kc];
        half8 hv = shv[kc];
#pragma unroll
        for (int t = 0; t < 4; t++) {
            int ma = wm + t * 16 + lrow;
            int ca = kc * 4 + quad;
            half8 a = *(const half8*)((const char*)smem +
                                      (ma * 32 + (ca ^ (ma & 7))) * 16);
            af[t] = __builtin_elementwise_max(a * sv + hv, zerov);
            bf[t] = *(const half8*)(Wt + (size_t)(col0 + wn + t * 16 + lrow) * 256 +
                                    kc * 32 + quad * 8);
        }
#pragma unroll
        for (int i = 0; i < 4; i++)
#pragma unroll
            for (int j2 = 0; j2 < 4; j2++)
                acc[i][j2] = __builtin_amdgcn_mfma_f32_16x16x32_f16(
                    af[i], bf[j2], acc[i][j2], 0, 0, 0);
    }

    GEMM_EPILOGUE
}

// ---------------------------------------------------------------------------
// Finalize BN from 32 replicated stat slots (dedicated buffer, no zeroing).
// ---------------------------------------------------------------------------
__global__ __launch_bounds__(256) void bn_finalize(const float* __restrict__ stats,
                                                   const float* __restrict__ g,
                                                   const float* __restrict__ beta,
                                                   float* __restrict__ scsh,
                                                   int n) {
    int d = threadIdx.x;
    float s = 0.0f, sq = 0.0f;
#pragma unroll 8
    for (int r = 0; r < 32; r++) {
        s += stats[r * 512 + d];
        sq += stats[r * 512 + 256 + d];
    }
    float invn = 1.0f / (float)n;
    float mean = s * invn;
    float var = sq * invn - mean * mean;
    float inv = rsqrtf(var + 1e-5f);
    float scale = g[d] * inv;
    scsh[d] = scale;
    scsh[DIM + d] = beta[d] - mean * scale;
}

// ---------------------------------------------------------------------------
// Final BN apply (layer 4): no relu, fp32 out.
// ---------------------------------------------------------------------------
__global__ __launch_bounds__(256) void bn_apply_f(const _Float16* __restrict__ in,
                                                  float* __restrict__ outf,
                                                  const float* __restrict__ scsh) {
    size_t i = (size_t)blockIdx.x * 256 + threadIdx.x;
    int c4 = (int)(i & 63);
    float4 sc = ((const float4*)scsh)[c4];
    float4 sh = ((const float4*)(scsh + DIM))[c4];
    half4 v = ((const half4*)in)[i];
    float4 o;
    o.x = (float)v.x * sc.x + sh.x;
    o.y = (float)v.y * sc.y + sh.y;
    o.z = (float)v.z * sc.z + sh.z;
    o.w = (float)v.w * sc.w + sh.w;
    ((float4*)outf)[i] = o;
}

// ---------------------------------------------------------------------------
extern "C" void kernel_launch(void* const* d_in, const int* in_sizes, int n_in,
                              void* d_out, int out_size, void* d_ws, size_t ws_size,
                              hipStream_t stream) {
    (void)in_sizes; (void)n_in; (void)out_size; (void)ws_size;
    const float* x   = (const float*)d_in[0];
    const int*   src = (const int*)d_in[1];
    const int*   dst = (const int*)d_in[2];
    const float* W1  = (const float*)d_in[3];
    const float* b1  = (const float*)d_in[4];
    const float* g1  = (const float*)d_in[5];
    const float* bt1 = (const float*)d_in[6];
    const float* W2  = (const float*)d_in[7];
    const float* b2  = (const float*)d_in[8];
    const float* eps = (const float*)d_in[9];
    const float* bng = (const float*)d_in[10];
    const float* bnb = (const float*)d_in[11];
    float* out = (float*)d_out;

    const int N = N_NODES, E = N_EDGES, D = DIM;
    size_t NDp = (size_t)MPAD * D;

    _Float16* gin  = (_Float16*)d_ws;              // gather output / GEMM1 in
    _Float16* C1   = gin + NDp;                    // GEMM1 raw out (also xh @ l0)
    _Float16* C2   = C1 + NDp;                     // GEMM2 raw out
    _Float16* Wt   = C2 + NDp;                     // 10 * 256*256 fp16
    float* statsG = (float*)(Wt + 10 * 65536);     // 10 sets * 32 replicas * 512
    float* scshA = statsG + 10 * 32 * 512;         // 512 f (BN1)
    float* scshB = scshA + 512;                    // 512 f (BN2)
    int* deg     = (int*)(scshB + 512);            // N (cursor)
    int* ptr     = deg + N;                        // N+1
    int* bsum    = ptr + N + 1;                    // 64
    int* srcbuf  = bsum + 64;                      // E

    const int ELEM4_BLOCKS = N * D / 4 / 256;      // 12500
    const int NODE_BLOCKS  = (N + 3) / 4;          // 12500
    const int E_BLOCKS     = (E + 255) / 256;      // 1172
    const int SCAN_BLOCKS  = (N + 1023) / 1024;    // 49
    const dim3 GEMM_GRID(2, MPAD / 128);           // (2, 391)

    // ---- One-time per call: CSR build, stats zero, conversions ----
    hipMemsetAsync(deg, 0, N * sizeof(int), stream);
    hipMemsetAsync(statsG, 0, 10 * 32 * 512 * sizeof(float), stream);
    hist_dst<<<E_BLOCKS, 256, 0, stream>>>(dst, deg, E);
    scan_blk<<<SCAN_BLOCKS, 1024, 0, stream>>>(deg, ptr, bsum, N);
    scan_top<<<1, 64, 0, stream>>>(bsum, ptr, SCAN_BLOCKS, N, E);
    scan_add<<<SCAN_BLOCKS, 1024, 0, stream>>>(ptr, bsum, deg, N);
    scatter_src<<<E_BLOCKS, 256, 0, stream>>>(src, dst, deg, srcbuf, E);
    wconv<<<160, 256, 0, stream>>>(W1, W2, Wt);
    x2h<<<ELEM4_BLOCKS, 256, 0, stream>>>(x, C1);  // C1 = xh for layer 0

    for (int l = 0; l < 5; l++) {
        float* stA = statsG + (size_t)(l * 2) * 32 * 512;
        float* stB = statsG + (size_t)(l * 2 + 1) * 32 * 512;

        // Gather (+ fused BN2-of-previous-layer for l>=1) -> gin (fp16)
        if (l == 0)
            gather_h<<<NODE_BLOCKS, 256, 0, stream>>>(C1, ptr, srcbuf, gin, eps);
        else
            gather_bn<<<NODE_BLOCKS, 256, 0, stream>>>(C2, ptr, srcbuf, gin,
                                                       scshB, eps, l);

        // C1 = gin @ W1 + b1 (raw), fused BN1 stats
        gemm_f16<<<GEMM_GRID, 256, 0, stream>>>(
            gin, Wt + (size_t)l * 65536, b1 + (size_t)l * D, C1, stA, N);
        bn_finalize<<<1, 256, 0, stream>>>(stA, g1 + (size_t)l * D,
                                           bt1 + (size_t)l * D, scshA, N);

        // C2 = relu(BN1(C1)) @ W2 + b2 (raw), fused BN2 stats
        gemm_bn<<<GEMM_GRID, 256, 0, stream>>>(
            C1, Wt + (size_t)(5 + l) * 65536, b2 + (size_t)l * D, scshA,
            C2, stB, N);
        bn_finalize<<<1, 256, 0, stream>>>(stB, bng + (size_t)l * D,
                                           bnb + (size_t)l * D, scshB, N);

        // BN2 consumed fused in next layer's gather; final layer writes out.
        if (l == 4)
            bn_apply_f<<<ELEM4_BLOCKS, 256, 0, stream>>>(C2, out, scshB);
    }
}